// Round 17
// baseline (34.690 us; speedup 1.0000x reference)
//
#include <hip/hip_runtime.h>
#include <math.h>

#define B_ 4
#define C_ 32
#define H_ 256
#define W_ 256
#define HW_ (H_ * W_)
#define K_ 9
#define TX 32
#define TY 4
#define HX 34              // TX + 2
#define HY 6               // TY + 2
#define HCH (HX * HY)      // 204 real halo positions; padded to 256/oct in LDS
#define NOCT 4
#define EPS_ 1e-12f

typedef _Float16 h2v __attribute__((ext_vector_type(2)));
typedef _Float16 h8v __attribute__((ext_vector_type(8)));

#if defined(__has_builtin)
#if __has_builtin(__builtin_amdgcn_fdot2)
#define HAVE_FDOT2 1
#endif
#if __has_builtin(__builtin_amdgcn_cvt_pkrtz)
#define HAVE_PKRTZ 1
#endif
#if __has_builtin(__builtin_amdgcn_rsqf)
#define RSQ(xx) __builtin_amdgcn_rsqf(xx)
#else
#define RSQ(xx) (1.0f / sqrtf(xx))
#endif
#else
#define RSQ(xx) (1.0f / sqrtf(xx))
#endif

static __device__ __forceinline__ h2v pk2(float a, float b) {
#if defined(HAVE_PKRTZ)
    return __builtin_bit_cast(h2v, __builtin_amdgcn_cvt_pkrtz(a, b));
#else
    h2v r = {(_Float16)a, (_Float16)b};
    return r;
#endif
}

static __device__ __forceinline__ float dot2(h2v a, h2v b, float c) {
#if defined(HAVE_FDOT2)
    return __builtin_amdgcn_fdot2(a, b, c, false);
#else
    return c + (float)a[0] * (float)b[0] + (float)a[1] * (float)b[1];
#endif
}

// R16 (32.1us) + sq-precompute: psq[k] = ||fu patch||^2 is a PER-POSITION
// quantity (shared by the 9 pixels tapping it), and staging thread t owns
// position t for ALL 4 octs (u=t+j*256 -> pos==t), so the full 32-ch sq[t]
// is computed locally during staging (32 fma, 1 b32 write, no extra barrier)
// and pass-1 just reads sq[hc+koff[k]]: -72 fdot2, -9 shuffles per thread.
// Also: single staging descriptor (pos==t for all units), rsq-based cosine,
// fu loads issued before fe-dependent converts (fu gates the barrier).
// LDS 17 KB -> still 8 blocks/CU (wave-limited); grid 2048 = exact fill.
// launch_bounds(256,6): ledger's clean bound (cap ~85, peak live ~60).
__global__ __launch_bounds__(256, 6) void asfr_kernel(const float* __restrict__ fe,
                                                      const float* __restrict__ fu,
                                                      float* __restrict__ out) {
    __shared__ h8v lds8[NOCT * 256];   // 16 KB padded halo
    __shared__ float sqb[256];         // 1 KB per-position ||patch||^2
    const int t = threadIdx.x;
    const int bx = blockIdx.x & 7;           // W_/TX = 8
    const int by = (blockIdx.x >> 3) & 63;   // H_/TY = 64
    const int b  = blockIdx.x >> 9;
    const int w0 = bx * TX, h0 = by * TY;

    const int x = t & 31;
    const int half = (t >> 5) & 1;
    const int y = t >> 6;
    const int c0 = half << 4;
    const int pxoff = b * (C_ * HW_) + (h0 + y) * W_ + (w0 + x);

    // single staging descriptor: this thread stages position t of every oct
    int spat;
    float msk;
    {
        int pos = t;
        int pp = pos < HCH ? pos : HCH - 1;
        int r = pp / HX;
        int col = pp - r * HX;
        int hh = h0 - 1 + r;
        int ww = w0 - 1 + col;
        bool ok = (pos < HCH) && ((unsigned)hh < (unsigned)H_) && ((unsigned)ww < (unsigned)W_);
        int hcl = hh < 0 ? 0 : (hh > H_ - 1 ? H_ - 1 : hh);
        int wcl = ww < 0 ? 0 : (ww > W_ - 1 ? W_ - 1 : ww);
        spat = hcl * W_ + wcl;
        msk = ok ? 1.f : 0.f;
    }

    // ---- fu staging loads FIRST (they gate the barrier): all 32 in flight
    const float* fub = fu + b * (C_ * HW_);
    float s[32];
#pragma unroll
    for (int c = 0; c < 32; ++c) s[c] = fub[c * HW_ + spat];

    // fe loads (consumed after barrier; latency hides under stage+pass1 entry)
    float fv[16];
#pragma unroll
    for (int cc = 0; cc < 16; ++cc) fv[cc] = fe[pxoff + (c0 + cc) * HW_];

    // per-position full-channel squared norm (f32-exact) + convert + LDS write
    float part = 0.f;
#pragma unroll
    for (int c = 0; c < 32; ++c) part = fmaf(s[c], s[c], part);
    sqb[t] = msk * part;
#pragma unroll
    for (int j = 0; j < 4; ++j) {
        h8v hv;
#pragma unroll
        for (int c = 0; c < 4; ++c) {
            h2v p = pk2(s[8 * j + 2 * c] * msk, s[8 * j + 2 * c + 1] * msk);
            hv[2 * c] = p[0];
            hv[2 * c + 1] = p[1];
        }
        lds8[t + j * 256] = hv;
    }

    // fe: f32 fsq + h8 conversion
    float fsq = 0.f;
#pragma unroll
    for (int cc = 0; cc < 16; ++cc) fsq = fmaf(fv[cc], fv[cc], fsq);
    h8v fe8[2];
#pragma unroll
    for (int j = 0; j < 2; ++j)
#pragma unroll
        for (int c = 0; c < 4; ++c) {
            h2v p = pk2(fv[8 * j + 2 * c], fv[8 * j + 2 * c + 1]);
            fe8[j][2 * c] = p[0];
            fe8[j][2 * c + 1] = p[1];
        }
    __syncthreads();

    const int hc = (y + 1) * HX + (x + 1);
    const int koff[K_] = {-HX - 1, -HX, -HX + 1, -1, 0, 1, HX - 1, HX, HX + 1};

    // psq[k] comes straight from the per-position table (full 32 channels)
    float psq[K_];
#pragma unroll
    for (int k = 0; k < K_; ++k) psq[k] = sqb[hc + koff[k]];

    float dot[K_];
#pragma unroll
    for (int k = 0; k < K_; ++k) dot[k] = 0.f;

    // Pass 1: dot only (4 fdot2/tap/oct); b128 taps
#pragma unroll
    for (int j = 0; j < 2; ++j) {
        const int oct = 2 * half + j;
        h8v fq = fe8[j];
        h2v fA0 = __builtin_shufflevector(fq, fq, 0, 1);
        h2v fA1 = __builtin_shufflevector(fq, fq, 2, 3);
        h2v fA2 = __builtin_shufflevector(fq, fq, 4, 5);
        h2v fA3 = __builtin_shufflevector(fq, fq, 6, 7);
        const h8v* fubase = &lds8[(oct << 8) + hc];
#pragma unroll
        for (int k = 0; k < K_; ++k) {
            h8v p8 = fubase[koff[k]];
            dot[k] = dot2(__builtin_shufflevector(p8, p8, 0, 1), fA0, dot[k]);
            dot[k] = dot2(__builtin_shufflevector(p8, p8, 2, 3), fA1, dot[k]);
            dot[k] = dot2(__builtin_shufflevector(p8, p8, 4, 5), fA2, dot[k]);
            dot[k] = dot2(__builtin_shufflevector(p8, p8, 6, 7), fA3, dot[k]);
        }
    }

    // combine halves (dot, fsq only — psq is already full-channel)
#pragma unroll
    for (int k = 0; k < K_; ++k) dot[k] += __shfl_xor(dot[k], 32);
    fsq += __shfl_xor(fsq, 32);

    float cosv[K_], negd[K_];
#pragma unroll
    for (int k = 0; k < K_; ++k) {
        float prod = fmaxf(psq[k] * fsq, 1e-24f);
        cosv[k] = dot[k] * RSQ(prod);
        float dsq = fmaxf(psq[k] - 2.f * dot[k] + fsq, 0.f);   // ||p-f||^2
        negd[k] = -sqrtf(dsq);
    }

    float m1 = cosv[0], m2 = negd[0];
#pragma unroll
    for (int k = 1; k < K_; ++k) { m1 = fmaxf(m1, cosv[k]); m2 = fmaxf(m2, negd[k]); }
    float s1 = 0.f, s2 = 0.f, e1[K_], e2[K_];
#pragma unroll
    for (int k = 0; k < K_; ++k) {
        e1[k] = __expf(cosv[k] - m1);
        e2[k] = __expf(negd[k] - m2);
        s1 += e1[k]; s2 += e2[k];
    }
    float r1 = __fdividef(0.5f, s1), r2 = __fdividef(0.5f, s2);
    h2v w2[K_];
#pragma unroll
    for (int k = 0; k < K_; ++k) {
        float wk = fmaf(e1[k], r1, e2[k] * r2);
        _Float16 wh = (_Float16)wk;
        h2v tmp = {wh, wh};
        w2[k] = tmp;
    }

    // Pass 2: packed weighted gather (b128 taps) + f16 residual from regs
#pragma unroll
    for (int j = 0; j < 2; ++j) {
        const int oct = 2 * half + j;
        const h8v* fubase = &lds8[(oct << 8) + hc];
        h2v a0 = {(_Float16)0, (_Float16)0};
        h2v a1 = a0, a2 = a0, a3 = a0;
#pragma unroll
        for (int k = 0; k < K_; ++k) {
            h8v p8 = fubase[koff[k]];
            a0 += w2[k] * __builtin_shufflevector(p8, p8, 0, 1);
            a1 += w2[k] * __builtin_shufflevector(p8, p8, 2, 3);
            a2 += w2[k] * __builtin_shufflevector(p8, p8, 4, 5);
            a3 += w2[k] * __builtin_shufflevector(p8, p8, 6, 7);
        }
        h8v fq = fe8[j];
        const int cg = oct * 8;
        out[pxoff + (cg + 0) * HW_] = (float)(fq[0] + a0[0]);
        out[pxoff + (cg + 1) * HW_] = (float)(fq[1] + a0[1]);
        out[pxoff + (cg + 2) * HW_] = (float)(fq[2] + a1[0]);
        out[pxoff + (cg + 3) * HW_] = (float)(fq[3] + a1[1]);
        out[pxoff + (cg + 4) * HW_] = (float)(fq[4] + a2[0]);
        out[pxoff + (cg + 5) * HW_] = (float)(fq[5] + a2[1]);
        out[pxoff + (cg + 6) * HW_] = (float)(fq[6] + a3[0]);
        out[pxoff + (cg + 7) * HW_] = (float)(fq[7] + a3[1]);
    }
}

extern "C" void kernel_launch(void* const* d_in, const int* in_sizes, int n_in,
                              void* d_out, int out_size, void* d_ws, size_t ws_size,
                              hipStream_t stream) {
    const float* fe = (const float*)d_in[0];
    const float* fu = (const float*)d_in[1];
    float* out = (float*)d_out;
    dim3 grid((W_ / TX) * (H_ / TY) * B_), block(256);  // 2048 blocks = 8/CU exact
    hipLaunchKernelGGL(asfr_kernel, grid, block, 0, stream, fe, fu, out);
}